// Round 2
// baseline (630.669 us; speedup 1.0000x reference)
//
#include <hip/hip_runtime.h>
#include <cstdint>
#include <cstddef>

#define BATCH 64
#define CH 3
#define HH 256
#define WW 256
#define NBINS 256
#define TILE 32
#define HALO 5
#define HPAD 36                /* hA row stride (floats) */
#define NPB (CH*HH*WW)         /* 196608 elements per batch item */
#define EPX (NPB/8)            /* 24576 pixels per eighth-batch-item */
#define NHB 512                /* hist-role blocks (scheduled first) */
#define HWORDS 32768           /* u16-packed hist words per batch item (128 KB) */

__device__ __forceinline__ float block_reduce_256(float v, float* buf4) {
    #pragma unroll
    for (int o = 32; o > 0; o >>= 1) v += __shfl_down(v, o, 64);
    __syncthreads();
    int lane = threadIdx.x & 63;
    int wid  = threadIdx.x >> 6;
    if (lane == 0) buf4[wid] = v;
    __syncthreads();
    return buf4[0] + buf4[1] + buf4[2] + buf4[3];
}

__device__ __forceinline__ float block_reduce_1024(float v, float* buf16) {
    #pragma unroll
    for (int o = 32; o > 0; o >>= 1) v += __shfl_down(v, o, 64);
    __syncthreads();
    int lane = threadIdx.x & 63;
    int wid  = threadIdx.x >> 6;
    if (lane == 0) buf16[wid] = v;
    __syncthreads();
    float s = 0.0f;
    #pragma unroll
    for (int i = 0; i < 16; i++) s += buf16[i];
    return s;
}

// Heterogeneous mega-kernel.
//   bids [0,512):       hist role — pixels -> device-scope global atomicAdd
//                       into u16-packed per-item histogram (no LDS, no syncs)
//                       + per-wave MSE partials.
//   bids [512, 12800):  conv role — 32x32 separable-conv SSIM tiles,
//                       4 fields (x, y, x^2+y^2, x*y), 24.3 KB LDS.
// Dropping the 32 KB LDS u4-histogram union raises the conv occupancy cap
// from 5 to 6 blocks/CU and removes the 16 MB partial-flush traffic.
__global__ __launch_bounds__(256) void mega_kernel(
    const float* __restrict__ x, const float* __restrict__ y,
    const float* __restrict__ win,
    float* __restrict__ ssim_partials,
    unsigned int* __restrict__ hist, float* __restrict__ mse_part)
{
    __shared__ __align__(16) unsigned char smem[24320];
    const int bid = blockIdx.x;
    const int tid = threadIdx.x;

    if (bid < NHB) {
        // ================= hist role (no LDS) =================
        const int b = bid >> 3, e = bid & 7;
        const float4* x4 = (const float4*)x + (size_t)b * (NPB/4) + (size_t)e * (EPX/4);
        const float4* y4 = (const float4*)y + (size_t)b * (NPB/4) + (size_t)e * (EPX/4);
        unsigned int* hb = hist + (size_t)b * HWORDS;
        float mse_s = 0.0f;
        for (int i = 0; i < 24; i++) {
            float4 xv = x4[tid + i * 256];
            float4 yv = y4[tid + i * 256];
            float xs[4] = {xv.x, xv.y, xv.z, xv.w};
            float ys[4] = {yv.x, yv.y, yv.z, yv.w};
            #pragma unroll
            for (int q = 0; q < 4; q++) {
                float xc = xs[q], yc = ys[q];
                float d = xc - yc;
                mse_s += d * d;
                int ix = (int)(((xc + 1.0f) * 0.5f) * 256.0f);
                int iy = (int)(((yc + 1.0f) * 0.5f) * 256.0f);
                ix = min(max(ix, 0), 255);
                iy = min(max(iy, 0), 255);
                int key = ix * NBINS + iy;
                // u16-packed: word = key>>1, halfword = key&1. Counts stay
                // far below 65535 (random data), so halves never carry.
                atomicAdd(&hb[key >> 1], 1u << (16 * (key & 1)));
            }
        }
        // per-wave MSE partial
        #pragma unroll
        for (int o = 32; o > 0; o >>= 1) mse_s += __shfl_down(mse_s, o, 64);
        if ((tid & 63) == 0) mse_part[bid * 4 + (tid >> 6)] = mse_s;
        return;
    }

    // ================= conv role =================
    typedef float (*hA_t)[42][HPAD];
    hA_t hA = (hA_t)smem;                           // 4*42*36*4 = 24192 B
    float* g    = (float*)(smem + 24192);
    float* rbuf = (float*)(smem + 24256);

    const int cb = bid - NHB;
    const int tx = cb & 7, ty = (cb >> 3) & 7, z = cb >> 6;   // z = b*3 + c
    const float* xi = x + (size_t)z * (HH * WW);
    const float* yi = y + (size_t)z * (HH * WW);

    if (tid < 11) {
        float g5 = sqrtf(win[5*11 + 5]);
        g[tid] = win[5*11 + tid] / g5;
    }
    __syncthreads();

    // ---- Horizontal pass: 42 rows x 4 strips of 8 ----
    if (tid < 42 * 4) {
        int r = tid >> 2;
        int c0 = (tid & 3) * 8;
        int gr = ty * TILE - HALO + r;
        int gw = tx * TILE + c0 - HALO;       // gw % 8 == 3
        float xw[18], yw[18];
        bool rowok = (gr >= 0 && gr < HH);
        if (rowok) {
            const float* xr = xi + gr * WW;
            const float* yr = yi + gr * WW;
            int ga = gw - 3;
            if (ga >= 0 && ga + 24 <= WW) {
                float t0[24], t1[24];
                const float4* px4 = (const float4*)(xr + ga);
                const float4* py4 = (const float4*)(yr + ga);
                #pragma unroll
                for (int q = 0; q < 6; q++) {
                    float4 a = px4[q], bb = py4[q];
                    t0[q*4+0]=a.x; t0[q*4+1]=a.y; t0[q*4+2]=a.z; t0[q*4+3]=a.w;
                    t1[q*4+0]=bb.x; t1[q*4+1]=bb.y; t1[q*4+2]=bb.z; t1[q*4+3]=bb.w;
                }
                #pragma unroll
                for (int i = 0; i < 18; i++) { xw[i] = t0[3+i]; yw[i] = t1[3+i]; }
            } else {
                #pragma unroll
                for (int i = 0; i < 18; i++) {
                    int gc = gw + i;
                    bool ok = (gc >= 0 && gc < WW);
                    xw[i] = ok ? xr[gc] : 0.0f;
                    yw[i] = ok ? yr[gc] : 0.0f;
                }
            }
        } else {
            #pragma unroll
            for (int i = 0; i < 18; i++) { xw[i] = 0.0f; yw[i] = 0.0f; }
        }

        float aX[8], aY[8], aU[8], aV[8];
        #pragma unroll
        for (int j = 0; j < 8; j++) { aX[j]=0; aY[j]=0; aU[j]=0; aV[j]=0; }
        #pragma unroll
        for (int i = 0; i < 18; i++) {
            float xv = xw[i], yv = yw[i];
            float uu = xv * xv + yv * yv;
            float vv = xv * yv;
            #pragma unroll
            for (int j = 0; j < 8; j++) {
                int k = i - j;
                if (k >= 0 && k < 11) {
                    float w = g[k];
                    aX[j] += w * xv;
                    aY[j] += w * yv;
                    aU[j] += w * uu;
                    aV[j] += w * vv;
                }
            }
        }
        #pragma unroll
        for (int h = 0; h < 2; h++) {
            *(float4*)&hA[0][r][c0+4*h] = make_float4(aX[4*h], aX[4*h+1], aX[4*h+2], aX[4*h+3]);
            *(float4*)&hA[1][r][c0+4*h] = make_float4(aY[4*h], aY[4*h+1], aY[4*h+2], aY[4*h+3]);
            *(float4*)&hA[2][r][c0+4*h] = make_float4(aU[4*h], aU[4*h+1], aU[4*h+2], aU[4*h+3]);
            *(float4*)&hA[3][r][c0+4*h] = make_float4(aV[4*h], aV[4*h+1], aV[4*h+2], aV[4*h+3]);
        }
    }
    __syncthreads();

    // ---- Vertical pass ----
    const int c  = tid & 31;
    const int r0 = (tid >> 5) * 4;
    float mu1[4], mu2[4], euv[4], exy[4];
    #pragma unroll
    for (int j = 0; j < 4; j++) { mu1[j]=0; mu2[j]=0; euv[j]=0; exy[j]=0; }
    #pragma unroll
    for (int a = 0; a < 4; a++) {
        float v[14];
        #pragma unroll
        for (int i = 0; i < 14; i++) v[i] = hA[a][r0 + i][c];
        #pragma unroll
        for (int k = 0; k < 11; k++) {
            float w = g[k];
            #pragma unroll
            for (int j = 0; j < 4; j++) {
                float t = w * v[j + k];
                if (a == 0) mu1[j] += t;
                else if (a == 1) mu2[j] += t;
                else if (a == 2) euv[j] += t;
                else exy[j] += t;
            }
        }
    }

    float ssim_s = 0.0f;
    const float C1v = 1e-4f, C2v = 9e-4f;
    #pragma unroll
    for (int j = 0; j < 4; j++) {
        float m1 = mu1[j], m2 = mu2[j];
        float m1s = m1 * m1, m2s = m2 * m2, m12 = m1 * m2;
        float ssum = euv[j] - m1s - m2s;      // s1 + s2
        float s12  = exy[j] - m12;
        float num = (2.0f * m12 + C1v) * (2.0f * s12 + C2v);
        float den = (m1s + m2s + C1v) * (ssum + C2v);
        ssim_s += num / den;
    }

    float ssim_b = block_reduce_256(ssim_s, rbuf);
    if (tid == 0)
        ssim_partials[(size_t)z * 64 + ty * 8 + tx] = ssim_b;
}

// Fused merge+finalize: 64 blocks (one per batch item) x 1024 threads.
// Loop the 4 ix-slices; unpack u16 histogram words directly (no SWAR merge
// needed anymore); Hxy & Hx terms local; column partials accumulated in LDS
// per wave (fixed-lane ownership, no atomics); then Hy, SSIM, MSE, outputs.
__global__ __launch_bounds__(1024) void merge_finalize_kernel(
    const unsigned int* __restrict__ hist,
    const float* __restrict__ mse_part, const float* __restrict__ ssim_partials,
    float* __restrict__ out)
{
    __shared__ unsigned int colw[16][256];   // 16 KB per-wave column partials
    __shared__ float rbuf[16];
    const int b = blockIdx.x, t = threadIdx.x;
    const int w = t >> 6, l = t & 63;
    const float invN = 1.0f / (float)NPB;

    // zero per-wave column partials
    #pragma unroll
    for (int i = 0; i < 4; i++) ((unsigned int*)colw)[t + i * 1024] = 0;
    __syncthreads();

    float sxy = 0.0f, sx = 0.0f;
    for (int s = 0; s < 4; s++) {
        // thread t owns bins (row = s*64 + (t>>4), cols 16*(t&15)..+15):
        // 8 consecutive u16-packed words.
        const uint4* src = (const uint4*)(hist + (size_t)b * HWORDS + s * 8192 + t * 8);
        uint4 va = src[0], vb = src[1];
        unsigned int cnt[16];
        cnt[0]  = va.x & 0xFFFFu;  cnt[1]  = va.x >> 16;
        cnt[2]  = va.y & 0xFFFFu;  cnt[3]  = va.y >> 16;
        cnt[4]  = va.z & 0xFFFFu;  cnt[5]  = va.z >> 16;
        cnt[6]  = va.w & 0xFFFFu;  cnt[7]  = va.w >> 16;
        cnt[8]  = vb.x & 0xFFFFu;  cnt[9]  = vb.x >> 16;
        cnt[10] = vb.y & 0xFFFFu;  cnt[11] = vb.y >> 16;
        cnt[12] = vb.z & 0xFFFFu;  cnt[13] = vb.z >> 16;
        cnt[14] = vb.w & 0xFFFFu;  cnt[15] = vb.w >> 16;

        // Hxy terms + row count
        unsigned int rowc = 0;
        #pragma unroll
        for (int k = 0; k < 16; k++) {
            unsigned int v = cnt[k];
            rowc += v;
            if (v) {
                float jp = (float)v * invN;
                sxy += jp * __log2f(jp);
            }
        }
        #pragma unroll
        for (int o = 8; o > 0; o >>= 1) rowc += __shfl_xor((int)rowc, o, 16);
        if ((t & 15) == 0 && rowc) {
            float px = (float)rowc * invN;
            sx += px * __log2f(px);
        }

        // column partials: lanes l, l^16, l^32, l^48 own the same 16 cols
        #pragma unroll
        for (int k = 0; k < 16; k++) {
            cnt[k] += __shfl_xor((int)cnt[k], 16, 64);
            cnt[k] += __shfl_xor((int)cnt[k], 32, 64);
        }
        if (l < 16) {
            #pragma unroll
            for (int k = 0; k < 16; k++) colw[w][16 * l + k] += cnt[k];
        }
        // no sync needed: each LDS slot is owned by a fixed lane across s
    }

    float sxy_blk = block_reduce_1024(sxy, rbuf);   // syncs order colw writes
    float sx_blk  = block_reduce_1024(sx, rbuf);

    // Hy from total column counts
    float ey = 0.0f;
    if (t < 256) {
        unsigned int pc = 0;
        #pragma unroll
        for (int ww = 0; ww < 16; ww++) pc += colw[ww][t];
        if (pc) {
            float py = (float)pc * invN;
            ey = -py * __log2f(py);
        }
    }
    float hy = block_reduce_1024(ey, rbuf);
    float ssim_total = block_reduce_1024(
        (t < 192) ? ssim_partials[(size_t)b * 192 + t] : 0.0f, rbuf);
    float mse_all = block_reduce_1024(
        (t < 32) ? mse_part[b * 32 + t] : 0.0f, rbuf);

    if (t == 0) {
        float hxy = -sxy_blk;
        float hx  = -sx_blk;
        float mi = hx + hy - hxy;
        float norm = fminf(hx, hy);
        float m = (norm > 0.0f) ? (mi / norm) : 0.0f;
        m = fminf(fmaxf(m, 0.0f), 1.0f);
        out[b * 3 + 0] = m;
        out[b * 3 + 1] = ssim_total * invN;
        double mse = (double)mse_all * (1.0 / (4.0 * (double)NPB));
        out[b * 3 + 2] = (mse == 0.0) ? 2.5f : (float)(-10.0 * log10(mse) / 40.0);
    }
}

extern "C" void kernel_launch(void* const* d_in, const int* in_sizes, int n_in,
                              void* d_out, int out_size, void* d_ws, size_t ws_size,
                              hipStream_t stream) {
    const float* x   = (const float*)d_in[0];
    const float* y   = (const float*)d_in[1];
    const float* win = (const float*)d_in[2];
    float* out = (float*)d_out;

    // ws layout:
    //   hist:          64 * 32768 u32 (u16-packed)  8 MB
    //   mse_part:      2048 f32
    //   ssim_partials: 12288 f32
    char* p = (char*)d_ws;
    unsigned int* hist = (unsigned int*)p;
    size_t off = (size_t)BATCH * HWORDS * sizeof(unsigned int);
    float* mse_part = (float*)(p + off);        off += (size_t)NHB * 4 * sizeof(float);
    float* ssim_partials = (float*)(p + off);

    // zero the histogram (stream-ordered, graph-capturable)
    hipMemsetAsync(hist, 0, (size_t)BATCH * HWORDS * sizeof(unsigned int), stream);

    mega_kernel<<<dim3(NHB + 8 * 8 * BATCH * CH), dim3(256), 0, stream>>>(
        x, y, win, ssim_partials, hist, mse_part);
    merge_finalize_kernel<<<dim3(BATCH), dim3(1024), 0, stream>>>(
        hist, mse_part, ssim_partials, out);
}

// Round 3
// 183.665 us; speedup vs baseline: 3.4338x; 3.4338x over previous
//
#include <hip/hip_runtime.h>
#include <cstdint>
#include <cstddef>

#define BATCH 64
#define CH 3
#define HH 256
#define WW 256
#define NBINS 256
#define TILE 32
#define HALO 5
#define NPB (CH*HH*WW)         /* 196608 elements per batch item */
#define QPX (NPB/4)            /* 49152 pixels per quarter-batch-item */
#define NHB 256                /* hist-role blocks (scheduled first) */

__device__ __forceinline__ float block_reduce_256(float v, float* buf4) {
    #pragma unroll
    for (int o = 32; o > 0; o >>= 1) v += __shfl_down(v, o, 64);
    __syncthreads();
    int lane = threadIdx.x & 63;
    int wid  = threadIdx.x >> 6;
    if (lane == 0) buf4[wid] = v;
    __syncthreads();
    return buf4[0] + buf4[1] + buf4[2] + buf4[3];
}

__device__ __forceinline__ float block_reduce_1024(float v, float* buf16) {
    #pragma unroll
    for (int o = 32; o > 0; o >>= 1) v += __shfl_down(v, o, 64);
    __syncthreads();
    int lane = threadIdx.x & 63;
    int wid  = threadIdx.x >> 6;
    if (lane == 0) buf16[wid] = v;
    __syncthreads();
    float s = 0.0f;
    #pragma unroll
    for (int i = 0; i < 16; i++) s += buf16[i];
    return s;
}

// Heterogeneous mega-kernel.
//   bids [0,256):       hist role — u4-packed 256x256 LDS histogram partial
//                       (quarter batch item each) + per-wave MSE partials.
//   bids [256, 12544):  conv role — 32x32 separable-conv SSIM tiles,
//                       4 fields (x, y, x^2+y^2, x*y) INTERLEAVED as one
//                       float4 LDS plane so the vertical pass reads all 4
//                       fields with a single ds_read_b128 per (row,col).
// 32 KB LDS union (hist needs all 32 KB for 65536 u4 bins).
__global__ __launch_bounds__(256) void mega_kernel(
    const float* __restrict__ x, const float* __restrict__ y,
    const float* __restrict__ win,
    float* __restrict__ ssim_partials,
    unsigned int* __restrict__ u4hist, float* __restrict__ mse_part)
{
    __shared__ __align__(16) unsigned char smem[32768];
    const int bid = blockIdx.x;
    const int tid = threadIdx.x;

    if (bid < NHB) {
        // ================= hist role =================
        unsigned int* h32 = (unsigned int*)smem;   // 8192 words, 8 u4 bins each
        uint4* h128 = (uint4*)h32;
        #pragma unroll
        for (int i = 0; i < 8; i++) h128[tid + i * 256] = make_uint4(0, 0, 0, 0);
        __syncthreads();

        const int b = bid >> 2, e = bid & 3;
        const float4* x4 = (const float4*)x + (size_t)b * (NPB/4) + (size_t)e * (QPX/4);
        const float4* y4 = (const float4*)y + (size_t)b * (NPB/4) + (size_t)e * (QPX/4);
        float mse_s = 0.0f;
        for (int i = 0; i < 48; i++) {
            float4 xv = x4[tid + i * 256];
            float4 yv = y4[tid + i * 256];
            float xs[4] = {xv.x, xv.y, xv.z, xv.w};
            float ys[4] = {yv.x, yv.y, yv.z, yv.w};
            #pragma unroll
            for (int q = 0; q < 4; q++) {
                float xc = xs[q], yc = ys[q];
                float d = xc - yc;
                mse_s += d * d;
                int ix = (int)(((xc + 1.0f) * 0.5f) * 256.0f);
                int iy = (int)(((yc + 1.0f) * 0.5f) * 256.0f);
                ix = min(max(ix, 0), 255);
                iy = min(max(iy, 0), 255);
                int key = ix * NBINS + iy;
                atomicAdd(&h32[key >> 3], 1u << (4 * (key & 7)));
            }
        }
        // per-wave MSE partial (16 per batch item)
        #pragma unroll
        for (int o = 32; o > 0; o >>= 1) mse_s += __shfl_down(mse_s, o, 64);
        if ((tid & 63) == 0) mse_part[bid * 4 + (tid >> 6)] = mse_s;
        __syncthreads();

        // store u4 partial (coalesced)
        #pragma unroll
        for (int k = 0; k < 32; k++)
            u4hist[(size_t)bid * 8192 + tid + k * 256] = h32[tid + k * 256];
        return;
    }

    // ================= conv role =================
    typedef float4 (*hA4_t)[33];                    // 42*33*16 = 22176 B
    hA4_t hA4 = (hA4_t)smem;
    float* g    = (float*)(smem + 22176);
    float* rbuf = (float*)(smem + 22240);

    const int cb = bid - NHB;
    const int tx = cb & 7, ty = (cb >> 3) & 7, z = cb >> 6;   // z = b*3 + c
    const float* xi = x + (size_t)z * (HH * WW);
    const float* yi = y + (size_t)z * (HH * WW);

    if (tid < 11) {
        float g5 = sqrtf(win[5*11 + 5]);
        g[tid] = win[5*11 + tid] / g5;
    }
    __syncthreads();

    // ---- Horizontal pass: 42 rows x 4 strips of 8 ----
    if (tid < 42 * 4) {
        int r = tid >> 2;
        int c0 = (tid & 3) * 8;
        int gr = ty * TILE - HALO + r;
        int gw = tx * TILE + c0 - HALO;       // gw % 8 == 3
        float xw[18], yw[18];
        bool rowok = (gr >= 0 && gr < HH);
        if (rowok) {
            const float* xr = xi + gr * WW;
            const float* yr = yi + gr * WW;
            int ga = gw - 3;
            if (ga >= 0 && ga + 24 <= WW) {
                float t0[24], t1[24];
                const float4* px4 = (const float4*)(xr + ga);
                const float4* py4 = (const float4*)(yr + ga);
                #pragma unroll
                for (int q = 0; q < 6; q++) {
                    float4 a = px4[q], bb = py4[q];
                    t0[q*4+0]=a.x; t0[q*4+1]=a.y; t0[q*4+2]=a.z; t0[q*4+3]=a.w;
                    t1[q*4+0]=bb.x; t1[q*4+1]=bb.y; t1[q*4+2]=bb.z; t1[q*4+3]=bb.w;
                }
                #pragma unroll
                for (int i = 0; i < 18; i++) { xw[i] = t0[3+i]; yw[i] = t1[3+i]; }
            } else {
                #pragma unroll
                for (int i = 0; i < 18; i++) {
                    int gc = gw + i;
                    bool ok = (gc >= 0 && gc < WW);
                    xw[i] = ok ? xr[gc] : 0.0f;
                    yw[i] = ok ? yr[gc] : 0.0f;
                }
            }
        } else {
            #pragma unroll
            for (int i = 0; i < 18; i++) { xw[i] = 0.0f; yw[i] = 0.0f; }
        }

        float aX[8], aY[8], aU[8], aV[8];
        #pragma unroll
        for (int j = 0; j < 8; j++) { aX[j]=0; aY[j]=0; aU[j]=0; aV[j]=0; }
        #pragma unroll
        for (int i = 0; i < 18; i++) {
            float xv = xw[i], yv = yw[i];
            float uu = xv * xv + yv * yv;
            float vv = xv * yv;
            #pragma unroll
            for (int j = 0; j < 8; j++) {
                int k = i - j;
                if (k >= 0 && k < 11) {
                    float w = g[k];
                    aX[j] += w * xv;
                    aY[j] += w * yv;
                    aU[j] += w * uu;
                    aV[j] += w * vv;
                }
            }
        }
        #pragma unroll
        for (int j = 0; j < 8; j++)
            hA4[r][c0 + j] = make_float4(aX[j], aY[j], aU[j], aV[j]);
    }
    __syncthreads();

    // ---- Vertical pass: one ds_read_b128 per (row,col) covers all fields ----
    const int c  = tid & 31;
    const int r0 = (tid >> 5) * 4;
    float mu1[4], mu2[4], euv[4], exy[4];
    #pragma unroll
    for (int j = 0; j < 4; j++) { mu1[j]=0; mu2[j]=0; euv[j]=0; exy[j]=0; }
    #pragma unroll
    for (int i = 0; i < 14; i++) {
        float4 v = hA4[r0 + i][c];
        #pragma unroll
        for (int j = 0; j < 4; j++) {
            int k = i - j;
            if (k >= 0 && k < 11) {
                float w = g[k];
                mu1[j] += w * v.x;
                mu2[j] += w * v.y;
                euv[j] += w * v.z;
                exy[j] += w * v.w;
            }
        }
    }

    float ssim_s = 0.0f;
    const float C1v = 1e-4f, C2v = 9e-4f;
    #pragma unroll
    for (int j = 0; j < 4; j++) {
        float m1 = mu1[j], m2 = mu2[j];
        float m1s = m1 * m1, m2s = m2 * m2, m12 = m1 * m2;
        float ssum = euv[j] - m1s - m2s;      // s1 + s2
        float s12  = exy[j] - m12;
        float num = (2.0f * m12 + C1v) * (2.0f * s12 + C2v);
        float den = (m1s + m2s + C1v) * (ssum + C2v);
        ssim_s += num / den;
    }

    float ssim_b = block_reduce_256(ssim_s, rbuf);
    if (tid == 0)
        ssim_partials[(size_t)z * 64 + ty * 8 + tx] = ssim_b;
}

// Fused merge+finalize: 64 blocks (one per batch item) x 1024 threads.
// Loop the 4 ix-slices; SWAR-merge the 4 u4 partials per slice (4*15=60<255,
// carry-safe); Hxy & Hx terms local; column partials accumulated in LDS per
// wave (fixed-lane ownership, no atomics); then Hy, SSIM, MSE, outputs.
__global__ __launch_bounds__(1024) void merge_finalize_kernel(
    const unsigned int* __restrict__ u4hist,
    const float* __restrict__ mse_part, const float* __restrict__ ssim_partials,
    float* __restrict__ out)
{
    __shared__ unsigned int colw[16][256];   // 16 KB per-wave column partials
    __shared__ float rbuf[16];
    const int b = blockIdx.x, t = threadIdx.x;
    const int w = t >> 6, l = t & 63;
    const float invN = 1.0f / (float)NPB;

    // zero per-wave column partials
    #pragma unroll
    for (int i = 0; i < 4; i++) ((unsigned int*)colw)[t + i * 1024] = 0;
    __syncthreads();

    float sxy = 0.0f, sx = 0.0f;
    for (int s = 0; s < 4; s++) {
        // merge 4 partials: thread t owns bins 16t..16t+15 of slice s
        unsigned int s0a = 0, s1a = 0, s0b = 0, s1b = 0;
        #pragma unroll
        for (int p = 0; p < 4; p++) {
            const uint2* src = (const uint2*)(u4hist + (size_t)(b * 4 + p) * 8192 + s * 2048);
            uint2 v = src[t];
            s0a += v.x & 0x0F0F0F0Fu;  s1a += (v.x >> 4) & 0x0F0F0F0Fu;
            s0b += v.y & 0x0F0F0F0Fu;  s1b += (v.y >> 4) & 0x0F0F0F0Fu;
        }
        unsigned int cnt[16];
        #pragma unroll
        for (int m = 0; m < 4; m++) {
            cnt[2*m]         = (s0a >> (8*m)) & 255u;
            cnt[2*m + 1]     = (s1a >> (8*m)) & 255u;
            cnt[8 + 2*m]     = (s0b >> (8*m)) & 255u;
            cnt[8 + 2*m + 1] = (s1b >> (8*m)) & 255u;
        }

        // Hxy terms + row count (row = s*64 + (t>>4), cols 16*(t&15)+k)
        unsigned int rowc = 0;
        #pragma unroll
        for (int k = 0; k < 16; k++) {
            unsigned int v = cnt[k];
            rowc += v;
            if (v) {
                float jp = (float)v * invN;
                sxy += jp * __log2f(jp);
            }
        }
        #pragma unroll
        for (int o = 8; o > 0; o >>= 1) rowc += __shfl_xor((int)rowc, o, 16);
        if ((t & 15) == 0 && rowc) {
            float px = (float)rowc * invN;
            sx += px * __log2f(px);
        }

        // column partials: lanes l, l^16, l^32, l^48 own the same 16 cols
        #pragma unroll
        for (int k = 0; k < 16; k++) {
            cnt[k] += __shfl_xor((int)cnt[k], 16, 64);
            cnt[k] += __shfl_xor((int)cnt[k], 32, 64);
        }
        if (l < 16) {
            #pragma unroll
            for (int k = 0; k < 16; k++) colw[w][16 * l + k] += cnt[k];
        }
        // no sync needed: each LDS slot is owned by a fixed lane across s
    }

    float sxy_blk = block_reduce_1024(sxy, rbuf);   // syncs order colw writes
    float sx_blk  = block_reduce_1024(sx, rbuf);

    // Hy from total column counts
    float ey = 0.0f;
    if (t < 256) {
        unsigned int pc = 0;
        #pragma unroll
        for (int ww = 0; ww < 16; ww++) pc += colw[ww][t];
        if (pc) {
            float py = (float)pc * invN;
            ey = -py * __log2f(py);
        }
    }
    float hy = block_reduce_1024(ey, rbuf);
    float ssim_total = block_reduce_1024(
        (t < 192) ? ssim_partials[(size_t)b * 192 + t] : 0.0f, rbuf);
    float mse_all = block_reduce_1024(
        (t < 16) ? mse_part[b * 16 + t] : 0.0f, rbuf);

    if (t == 0) {
        float hxy = -sxy_blk;
        float hx  = -sx_blk;
        float mi = hx + hy - hxy;
        float norm = fminf(hx, hy);
        float m = (norm > 0.0f) ? (mi / norm) : 0.0f;
        m = fminf(fmaxf(m, 0.0f), 1.0f);
        out[b * 3 + 0] = m;
        out[b * 3 + 1] = ssim_total * invN;
        double mse = (double)mse_all * (1.0 / (4.0 * (double)NPB));
        out[b * 3 + 2] = (mse == 0.0) ? 2.5f : (float)(-10.0 * log10(mse) / 40.0);
    }
}

extern "C" void kernel_launch(void* const* d_in, const int* in_sizes, int n_in,
                              void* d_out, int out_size, void* d_ws, size_t ws_size,
                              hipStream_t stream) {
    const float* x   = (const float*)d_in[0];
    const float* y   = (const float*)d_in[1];
    const float* win = (const float*)d_in[2];
    float* out = (float*)d_out;

    // ws layout (everything fully written before read; no memset, no fences):
    //   u4hist:        256*8192 u32   8 MB
    //   mse_part:      1024 f32
    //   ssim_partials: 12288 f32
    char* p = (char*)d_ws;
    unsigned int* u4hist = (unsigned int*)p;
    size_t off = (size_t)NHB * 8192 * sizeof(unsigned int);
    float* mse_part = (float*)(p + off);        off += (size_t)NHB * 4 * sizeof(float);
    float* ssim_partials = (float*)(p + off);

    mega_kernel<<<dim3(NHB + 8 * 8 * BATCH * CH), dim3(256), 0, stream>>>(
        x, y, win, ssim_partials, u4hist, mse_part);
    merge_finalize_kernel<<<dim3(BATCH), dim3(1024), 0, stream>>>(
        u4hist, mse_part, ssim_partials, out);
}